// Round 1
// baseline (194.508 us; speedup 1.0000x reference)
//
#include <hip/hip_runtime.h>

// UpFirDn 2x downsample: depthwise 4x4 FIR (separable binomial), stride 2,
// pad (1,1). x: (16,512,64,64) f32 -> out: (16,512,32,32) f32.
//
// One block per (n,c) image. Separable two-pass through LDS:
//   Stage 1: h[y][ow] = sum_j kh[j] * x[y][2*ow-1+j]   (64x32 into LDS, pitch 33)
//   Stage 2: out[oh][ow] = sum_i kv[i] * h[2*oh-1+i][ow]
// kh/kv are col/row sums of the flipped 4x4 kernel (exact separation for the
// binomial kernel; reference conv flips the kernel, symmetric here but we flip
// anyway for correctness).

#define IH 64
#define IW 64
#define OHN 32
#define OWN 32
#define HP 33   // hbuf pitch: odd -> 2-way (free) LDS bank pattern in both stages

__global__ __launch_bounds__(256) void upfirdn_down2_kernel(
    const float* __restrict__ x, const float* __restrict__ kk,
    float* __restrict__ out)
{
    __shared__ float hbuf[IH * HP];  // 64*33*4 = 8448 B

    const int t = threadIdx.x;
    const int img = blockIdx.x;
    const float* __restrict__ xi = x + (size_t)img * (IH * IW);
    float* __restrict__ oi = out + (size_t)img * (OHN * OWN);

    // --- separable weights from the (flipped) 4x4 kernel ------------------
    // W[i][j] = kk[3-i][3-j]; kv[i] = sum_j W[i][j] (row sums of flipped),
    // kh[j] = sum_i W[i][j] (col sums of flipped). Uniform scalar loads.
    float km[16];
#pragma unroll
    for (int i = 0; i < 16; ++i) km[i] = kk[i];
    const float kh0 = km[3] + km[7] + km[11] + km[15];
    const float kh1 = km[2] + km[6] + km[10] + km[14];
    const float kh2 = km[1] + km[5] + km[9]  + km[13];
    const float kh3 = km[0] + km[4] + km[8]  + km[12];
    const float kv0 = km[12] + km[13] + km[14] + km[15];
    const float kv1 = km[8]  + km[9]  + km[10] + km[11];
    const float kv2 = km[4]  + km[5]  + km[6]  + km[7];
    const float kv3 = km[0]  + km[1]  + km[2]  + km[3];

    // --- stage 1: horizontal filter into LDS ------------------------------
    // thread t: row y = t>>2, quarter q = t&3 -> covers ow in [8q, 8q+8)
    // needs input cols [16q-1, 16q+16]: 4 float4 + 2 edge scalars (zero pad).
    {
        const int y = t >> 2;
        const int q = t & 3;
        const float* row = xi + y * IW + q * 16;
        const float4 a0 = ((const float4*)row)[0];
        const float4 a1 = ((const float4*)row)[1];
        const float4 a2 = ((const float4*)row)[2];
        const float4 a3 = ((const float4*)row)[3];
        const float left  = (q > 0) ? row[-1] : 0.0f;
        const float right = (q < 3) ? row[16] : 0.0f;

        float v[18];
        v[0] = left;
        v[1] = a0.x;  v[2] = a0.y;  v[3] = a0.z;  v[4] = a0.w;
        v[5] = a1.x;  v[6] = a1.y;  v[7] = a1.z;  v[8] = a1.w;
        v[9] = a2.x;  v[10] = a2.y; v[11] = a2.z; v[12] = a2.w;
        v[13] = a3.x; v[14] = a3.y; v[15] = a3.z; v[16] = a3.w;
        v[17] = right;

        float* hb = &hbuf[y * HP + q * 8];
#pragma unroll
        for (int m = 0; m < 8; ++m) {
            // ow = 8q+m needs cols 16q + (2m-1 .. 2m+2) -> v[2m..2m+3]
            hb[m] = kh0 * v[2 * m] + kh1 * v[2 * m + 1]
                  + kh2 * v[2 * m + 2] + kh3 * v[2 * m + 3];
        }
    }
    __syncthreads();

    // --- stage 2: vertical filter, 4 outputs per thread -------------------
    // thread t: ow = t&31, group g = t>>5 -> oh in [4g, 4g+4)
    // needs h rows [8g-1, 8g+8]: 10 reads shared across the 4 outputs.
    {
        const int ow = t & 31;
        const int g = t >> 5;
        const int ybase = 8 * g - 1;
        float hr[10];
#pragma unroll
        for (int r = 0; r < 10; ++r) {
            const int yy = ybase + r;
            hr[r] = (yy >= 0 && yy < IH) ? hbuf[yy * HP + ow] : 0.0f;
        }
#pragma unroll
        for (int m = 0; m < 4; ++m) {
            const float o = kv0 * hr[2 * m] + kv1 * hr[2 * m + 1]
                          + kv2 * hr[2 * m + 2] + kv3 * hr[2 * m + 3];
            oi[(4 * g + m) * OWN + ow] = o;
        }
    }
}

extern "C" void kernel_launch(void* const* d_in, const int* in_sizes, int n_in,
                              void* d_out, int out_size, void* d_ws, size_t ws_size,
                              hipStream_t stream) {
    const float* x = (const float*)d_in[0];
    const float* k = (const float*)d_in[1];
    float* out = (float*)d_out;
    const int n_img = in_sizes[0] / (IH * IW);  // 16*512 = 8192
    upfirdn_down2_kernel<<<n_img, 256, 0, stream>>>(x, k, out);
}